// Round 9
// baseline (454.113 us; speedup 1.0000x reference)
//
#include <hip/hip_runtime.h>
#include <cstddef>

#define T_LEN 512
#define IN_D 8
#define H 32
#define NBATCH 16        // batches per WG (MFMA M)
#define NT 512           // 8 waves: wave w owns tile (gate g=w>>1, half d=w&1)
#define NCHUNK (T_LEN / 8)
#define LOG2E 1.44269504088896341f
#define GP 36            // G row pad (words): 144q%32=16 -> writes exact 2-way
#define NCUCTR 4096      // per-CU arrival counters in workspace

typedef __attribute__((ext_vector_type(8))) short bf16x8;
typedef __attribute__((ext_vector_type(4))) float f32x4;

__device__ __forceinline__ float fexp2(float v) { return __builtin_amdgcn_exp2f(v); }
__device__ __forceinline__ float frcp(float v)  { return __builtin_amdgcn_rcpf(v); }
__device__ __forceinline__ unsigned short f2bf(float f) {   // RNE fp32->bf16 (setup only)
    unsigned u = __builtin_bit_cast(unsigned, f);
    u += 0x7FFF + ((u >> 16) & 1);
    return (unsigned short)(u >> 16);
}
__device__ __forceinline__ float bf2f(unsigned short b) {
    unsigned u = ((unsigned)b) << 16;
    return __builtin_bit_cast(float, u);
}
__device__ __forceinline__ float ubits(unsigned u) { return __builtin_bit_cast(float, u); }
// packed RNE fp32x2 -> bf16x2 (arg0 -> low16, arg1 -> high16)
__device__ __forceinline__ unsigned cvt_pk_bf16(float lo, float hi) {
    unsigned r;
    asm("v_cvt_pk_bf16_f32 %0, %1, %2" : "=v"(r) : "v"(lo), "v"(hi));
    return r;
}

// LDS-only barrier: no vmcnt drain (global x-chunk loads stay in flight).
#define WG_BARRIER() asm volatile("s_waitcnt lgkmcnt(0)\n\ts_barrier" ::: "memory")

// R8 kernel (342us) + ANTI-PHASE SEEDING (the only change this round).
// Theory: the two co-resident WGs per CU run identical rigid barrier cadences
// and are dispatched simultaneously -> they stall in lockstep, leaving 46% of
// SIMD cycles with no issuable wave (R8 PMC: VALUBusy 54%, chain model ~850).
// Fix: WG's thread 0 atomically ranks its arrival on its physical CU (HW_ID/
// XCC_ID -> workspace counter); odd-rank WGs s_sleep ~800cyc (half a step)
// before the loop. Offset persists (identical cadence) -> each WG's chain
// stalls covered by the other WG's issue. Pure timing change; math identical.
__global__ void __launch_bounds__(NT, 4) lstm_mfma4(
    const float* __restrict__ x, const float* __restrict__ W_ih,
    const float* __restrict__ W_hh, const float* __restrict__ b_ih,
    const float* __restrict__ b_hh, const float* __restrict__ W_fc,
    const float* __restrict__ b_fc, float* __restrict__ out,
    unsigned* __restrict__ cuctr)
{
    __shared__ __align__(16) float G[4][NBATCH][GP];           // 9216 B, col = unit u
    __shared__ __align__(16) unsigned short hhi[NBATCH][48];   // 1536 B, pi-order k
    __shared__ __align__(16) unsigned short hlo[NBATCH][48];   // 1536 B
    __shared__ __align__(16) unsigned short xstg[8][17][24];   // 6528 B; cols 16-23 stay zero
    __shared__ unsigned sh_delay;

    const int tix  = threadIdx.x;
    const int w    = tix >> 6;
    const int g    = w >> 1;            // gate id (0=i,1=f,2=g,3=o)
    const int d    = w & 1;             // tile half
    const int lane = tix & 63;
    const int q    = lane >> 4;         // k-quad (A/B) / row-group (C)
    const int cc   = lane & 15;         // A row (batch) / B col (unit-in-tile)

    // ---- arrival-rank parity on this physical CU (robust to any WG->CU map) ----
    if (tix == 0) {
        unsigned delay = 0u;
        if (cuctr != nullptr) {
            unsigned hwid, xcc;
            asm volatile("s_getreg_b32 %0, hwreg(HW_REG_HW_ID)"  : "=s"(hwid));
            asm volatile("s_getreg_b32 %0, hwreg(HW_REG_XCC_ID)" : "=s"(xcc));
            const unsigned idx = (((xcc & 7u) << 8) | ((hwid >> 8) & 0xFFu)) & (NCUCTR - 1);
            const unsigned rank = atomicAdd(&cuctr[idx], 1u);
            delay = rank & 1u;
        }
        sh_delay = delay;
    }

    const float kk = (g == 2) ? 2.f * LOG2E : -LOG2E;
    const float aa = (g == 2) ? 2.f * LOG2E : 0.f;     // g stored as 2L*tanh(g)
    const float bb = (g == 2) ? -4.f * LOG2E : 1.f;

    // ---- static B fragments for tile (g,d) (premultiplied by kk) ----
    bf16x8 Bh, Bl, Bx;
    const int r = 16 * (2 * g + d) + cc;              // global gate-row
    #pragma unroll
    for (int j = 0; j < 8; ++j) {
        const int p = 8 * q + j;                      // k position (pi-order)
        const int u = 16 * (p & 1) + (p >> 1);        // unit index
        const float ws = kk * W_hh[r * H + u];
        const unsigned short whi = f2bf(ws);
        Bh[j] = (short)whi;
        Bl[j] = (short)f2bf(ws - bf2f(whi));
        if (q == 3) {
            Bx[j] = 0;                                 // zero k-quad
        } else {
            const float wsx = kk * W_ih[r * IN_D + j];
            const unsigned short xwh = f2bf(wsx);
            // q=0,1 multiply x_hi/x_lo by W_hi; q=2 multiplies x_hi by W_lo
            Bx[j] = (q == 2) ? (short)f2bf(wsx - bf2f(xwh)) : (short)xwh;
        }
    }
    const float bias = kk * (b_ih[r] + b_hh[r]);
    const f32x4 biasv = { bias, bias, bias, bias };

    // per-lane x A-frag offset: q0->xh, q1->xl, q2->xh (again), q3->zeros
    const int xoff = (q == 2) ? 0 : ((q == 3) ? 16 : 8 * q);

    // ---- x chunk machinery (first 256 threads): (batch xb, step xs, half xhf) ----
    const int xb = (tix >> 4) & 15, xs = (tix >> 1) & 7, xhf = tix & 1;
    const bool stager = (tix < 256);
    const float* xbase = x + (size_t)(blockIdx.x * NBATCH + xb) * (size_t)(T_LEN * IN_D)
                           + xs * IN_D + 4 * xhf;
    auto ldchunk = [&](int ch) { return *(const float4*)(xbase + (size_t)ch * 8 * IN_D); };
    auto stage = [&](float4 v) {
        const unsigned h0 = cvt_pk_bf16(v.x, v.y);
        const unsigned h1 = cvt_pk_bf16(v.z, v.w);
        const unsigned l0 = cvt_pk_bf16(v.x - ubits(h0 << 16), v.y - ubits(h0 & 0xffff0000u));
        const unsigned l1 = cvt_pk_bf16(v.z - ubits(h1 << 16), v.w - ubits(h1 & 0xffff0000u));
        *(uint2*)&xstg[xs][xb][4 * xhf]     = make_uint2(h0, h1);
        *(uint2*)&xstg[xs][xb][8 + 4 * xhf] = make_uint2(l0, l1);
    };

    // ---- init: zero h and xstg (zero regions persist), stage chunk 0 ----
    for (int i = tix; i < NBATCH * 48 / 2; i += NT) {
        ((unsigned*)hhi)[i] = 0u;
        ((unsigned*)hlo)[i] = 0u;
    }
    for (int i = tix; i < 8 * 17 * 24 / 2; i += NT) ((unsigned*)xstg)[i] = 0u;
    __syncthreads();

    // ---- anti-phase: odd-rank WG sleeps ~half a step (12*64 = 768 cyc) ----
    if (sh_delay) {
        asm volatile("s_sleep 6");
        asm volatile("s_sleep 6");
    }

    float4 xbuf = {0.f, 0.f, 0.f, 0.f};
    if (stager) {
        stage(ldchunk(0));
        xbuf = ldchunk(1);
    }
    __syncthreads();

    // ---- XC[s]: x-contribution + bias for this wave's tile (32 VGPRs) ----
    f32x4 XC[8];
    #pragma unroll
    for (int s = 0; s < 8; ++s) {
        const bf16x8 Ax_ = *(const bf16x8*)&xstg[s][cc][xoff];
        XC[s] = __builtin_amdgcn_mfma_f32_16x16x32_bf16(Ax_, Bx, biasv, 0, 0, 0);
    }

    // c/h ownership: 1 cell per thread: batch m, unit u
    const int m = tix >> 5, u = tix & 31;
    const float wfc = W_fc[u];
    float cs = 0.f, hf = 0.f;

    for (int blk = 0; blk < NCHUNK; ++blk) {
        #pragma unroll
        for (int s = 0; s < 8; ++s) {
            // ---- all LDS reads issued up front: h A-frags + refill operands ----
            const bf16x8 A0 = *(const bf16x8*)&hhi[cc][8 * q];
            const bf16x8 A2 = *(const bf16x8*)&hlo[cc][8 * q];
            bf16x8 Axp, Ax7;
            if (s >= 1)  Axp = *(const bf16x8*)&xstg[s - 1][cc][xoff];
            if (s == 7)  Ax7 = *(const bf16x8*)&xstg[7][cc][xoff];

            // ---- 3 INDEPENDENT MFMAs (chain = 1 MFMA latency + 2 adds) ----
            const f32x4 z = { 0.f, 0.f, 0.f, 0.f };
            f32x4 a1 = __builtin_amdgcn_mfma_f32_16x16x32_bf16(A0, Bh, XC[s], 0, 0, 0);
            f32x4 a2 = __builtin_amdgcn_mfma_f32_16x16x32_bf16(A2, Bh, z, 0, 0, 0);
            f32x4 a3 = __builtin_amdgcn_mfma_f32_16x16x32_bf16(A0, Bl, z, 0, 0, 0);

            // ---- next-chunk XC refill MFMAs (off critical path, reads hoisted) ----
            if (s >= 1)
                XC[s - 1] = __builtin_amdgcn_mfma_f32_16x16x32_bf16(Axp, Bx, biasv, 0, 0, 0);
            if (s == 7)
                XC[7] = __builtin_amdgcn_mfma_f32_16x16x32_bf16(Ax7, Bx, biasv, 0, 0, 0);

            // ---- stage next chunk early (s==0): consumed by refills from s==1 ----
            if (s == 0 && stager) {
                stage(xbuf);
                int nc = blk + 2;
                if (nc > NCHUNK - 1) nc = NCHUNK - 1;
                xbuf = ldchunk(nc);
            }

            // ---- activation (kk pre-folded) -> unit-major b32 G writes ----
            const f32x4 C = (a1 + a2) + a3;
            #pragma unroll
            for (int rg = 0; rg < 4; ++rg)
                G[g][4 * q + rg][cc + 16 * d] = aa + bb * frcp(1.f + fexp2(C[rg]));

            WG_BARRIER();

            // ---- non-redundant c/h update: 1 cell/thread, exp2-domain c ----
            {
                const float gi = G[0][m][u];
                const float gf = G[1][m][u];
                const float gg = G[2][m][u];
                const float go = G[3][m][u];
                cs = gf * cs + gi * gg;               // cs = 2L*c
                const float rr = frcp(1.f + fexp2(cs));
                hf = go - 2.f * go * rr;              // o * tanh(c)
                // pair (u, u+16) -> pi cols (2u', 2u'+1): partner via shfl
                const float hp = __shfl_xor(hf, 16);
                if ((tix & 16) == 0) {
                    const unsigned hw = cvt_pk_bf16(hf, hp);
                    const unsigned lw = cvt_pk_bf16(hf - ubits(hw << 16),
                                                    hp - ubits(hw & 0xffff0000u));
                    *(unsigned*)&hhi[m][2 * (u & 15)] = hw;
                    *(unsigned*)&hlo[m][2 * (u & 15)] = lw;
                }
            }

            WG_BARRIER();
        }
    }

    // ---- epilogue: out[b] = h_n . W_fc + b_fc (fp32 h, shfl reduce over u) ----
    float sacc = hf * wfc;
    sacc += __shfl_xor(sacc, 1);
    sacc += __shfl_xor(sacc, 2);
    sacc += __shfl_xor(sacc, 4);
    sacc += __shfl_xor(sacc, 8);
    sacc += __shfl_xor(sacc, 16);
    if ((tix & 31) == 0) out[blockIdx.x * NBATCH + m] = sacc + b_fc[0];
}

extern "C" void kernel_launch(void* const* d_in, const int* in_sizes, int n_in,
                              void* d_out, int out_size, void* d_ws, size_t ws_size,
                              hipStream_t stream) {
    const float* x    = (const float*)d_in[0];
    const float* W_ih = (const float*)d_in[1];
    const float* W_hh = (const float*)d_in[2];
    const float* b_ih = (const float*)d_in[3];
    const float* b_hh = (const float*)d_in[4];
    const float* W_fc = (const float*)d_in[5];
    const float* b_fc = (const float*)d_in[6];
    float* out = (float*)d_out;

    unsigned* cuctr = nullptr;
    if (d_ws != nullptr && ws_size >= NCUCTR * sizeof(unsigned)) {
        cuctr = (unsigned*)d_ws;
        hipMemsetAsync(cuctr, 0, NCUCTR * sizeof(unsigned), stream);
    }

    const int Bn = in_sizes[0] / (T_LEN * IN_D);   // 8192
    lstm_mfma4<<<dim3(Bn / NBATCH), dim3(NT), 0, stream>>>(
        x, W_ih, W_hh, b_ih, b_hh, W_fc, b_fc, out, cuctr);
}

// Round 10
// 388.245 us; speedup vs baseline: 1.1697x; 1.1697x over previous
//
#include <hip/hip_runtime.h>
#include <cstddef>

#define T_LEN 512
#define IN_D 8
#define H 32
#define NBATCH 16        // batches per WG (MFMA N now)
#define NT 512           // 8 waves: wave m owns units 4m..4m+3, ALL 4 gates
#define NCHUNK (T_LEN / 8)
#define LOG2E 1.44269504088896341f
#define CSCLAMP 88.f

typedef __attribute__((ext_vector_type(8))) short bf16x8;
typedef __attribute__((ext_vector_type(4))) float f32x4;

__device__ __forceinline__ float fexp2(float v) { return __builtin_amdgcn_exp2f(v); }
__device__ __forceinline__ float frcp(float v)  { return __builtin_amdgcn_rcpf(v); }
__device__ __forceinline__ unsigned short f2bf(float f) {   // RNE fp32->bf16 (setup only)
    unsigned u = __builtin_bit_cast(unsigned, f);
    u += 0x7FFF + ((u >> 16) & 1);
    return (unsigned short)(u >> 16);
}
__device__ __forceinline__ float bf2f(unsigned short b) {
    unsigned u = ((unsigned)b) << 16;
    return __builtin_bit_cast(float, u);
}
__device__ __forceinline__ float ubits(unsigned u) { return __builtin_bit_cast(float, u); }
// packed RNE fp32x2 -> bf16x2 (arg0 -> low16, arg1 -> high16)
__device__ __forceinline__ unsigned cvt_pk_bf16(float lo, float hi) {
    unsigned r;
    asm("v_cvt_pk_bf16_f32 %0, %1, %2" : "=v"(r) : "v"(lo), "v"(hi));
    return r;
}

// LDS-only barrier: no vmcnt drain (global x-chunk loads stay in flight).
#define WG_BARRIER() asm volatile("s_waitcnt lgkmcnt(0)\n\ts_barrier" ::: "memory")

// EXCHANGE-FREE tiling (R9 post-mortem: topology floor = 2 exchanges + 2
// barriers; kill the G-exchange). A/B roles swapped: A = WEIGHTS with tile m's
// 16 rows = units 4m..4m+3 x gates (i,f,g,o) INTERLEAVED (row cc -> gate cc&3,
// unit 4m+(cc>>2)); B = h (read hh[cc][8q] -- byte-identical frag read as
// before, operand layouts are symmetric). Then lane (q,cc) accumulates
// D[4q+reg][cc] = all 4 gate pre-acts (reg=i,f,g,o) of cell (unit 4m+q, batch
// cc) in-register: G exchange, its barrier, and its LDS traffic are GONE.
// Per step: 2 b128 h-reads, 3 indep MFMAs + 1 XC refill, merged-rcp cell math
// (R6-verified, 7 trans), 2 b16 h-writes, ONE barrier. h ping-pong buffered
// (parity compile-time in unrolled s-loop) makes the single barrier race-free.
// All 8 waves symmetric (R4/R5 lesson). Pitch 40: aligned b128, 2-way writes.
__global__ void __launch_bounds__(NT, 4) lstm_xfree(
    const float* __restrict__ x, const float* __restrict__ W_ih,
    const float* __restrict__ W_hh, const float* __restrict__ b_ih,
    const float* __restrict__ b_hh, const float* __restrict__ W_fc,
    const float* __restrict__ b_fc, float* __restrict__ out)
{
    __shared__ __align__(16) unsigned short hh[2][NBATCH][40];  // 2560 B [buf][batch][pi-k]
    __shared__ __align__(16) unsigned short hl[2][NBATCH][40];  // 2560 B
    __shared__ __align__(16) unsigned short xstg[8][17][24];    // 6528 B; cols 16-23 stay zero
    __shared__ float gpart[8][NBATCH];                          // 512 B epilogue partials

    const int tix  = threadIdx.x;
    const int m    = tix >> 6;          // wave id: units 4m..4m+3
    const int lane = tix & 63;
    const int q    = lane >> 4;         // k-quad (A/B) / D row-group
    const int cc   = lane & 15;         // A row (W-row) / B col (batch)

    // ---- static A fragments (weights, gate-interleaved rows, kk pre-folded) ----
    // A row cc of tile m: gate = cc&3, unit = 4m + (cc>>2)
    const int gate = cc & 3;
    const int urow = 4 * m + (cc >> 2);
    const int wrow = 32 * gate + urow;                // memory row in [4H]
    const float kk = (gate == 2) ? -2.f * LOG2E : -LOG2E;
    bf16x8 Whi, Wlo, Wx;
    #pragma unroll
    for (int j = 0; j < 8; ++j) {
        const int p = 8 * q + j;                      // k position (pi-order)
        const int u = 16 * (p & 1) + (p >> 1);        // unit index along K
        const float ws = kk * W_hh[wrow * H + u];
        const unsigned short whi = f2bf(ws);
        Whi[j] = (short)whi;
        Wlo[j] = (short)f2bf(ws - bf2f(whi));
        if (q == 3) {
            Wx[j] = 0;                                 // zero k-quad
        } else {
            const float wsx = kk * W_ih[wrow * IN_D + j];
            const unsigned short xwh = f2bf(wsx);
            // K-packed x: quads q0,q1 use W_hi (vs xh,xl), q2 uses W_lo (vs xh)
            Wx[j] = (q == 2) ? (short)f2bf(wsx - bf2f(xwh)) : (short)xwh;
        }
    }
    // per-reg bias: D row 4q+reg -> gate reg, unit 4m+q
    f32x4 biasv;
    #pragma unroll
    for (int reg = 0; reg < 4; ++reg) {
        const int br = 32 * reg + 4 * m + q;
        const float kkr = (reg == 2) ? -2.f * LOG2E : -LOG2E;
        biasv[reg] = kkr * (b_ih[br] + b_hh[br]);
    }

    // per-lane x B-frag offset: q0->xh, q1->xl, q2->xh (again), q3->zeros
    const int xoff = (q == 2) ? 0 : ((q == 3) ? 16 : 8 * q);

    // ---- x chunk machinery (first 256 threads): (batch xb, step xs, half xhf) ----
    const int xb = (tix >> 4) & 15, xs = (tix >> 1) & 7, xhf = tix & 1;
    const bool stager = (tix < 256);
    const float* xbase = x + (size_t)(blockIdx.x * NBATCH + xb) * (size_t)(T_LEN * IN_D)
                           + xs * IN_D + 4 * xhf;
    auto ldchunk = [&](int ch) { return *(const float4*)(xbase + (size_t)ch * 8 * IN_D); };
    auto stage = [&](float4 v) {
        const unsigned h0 = cvt_pk_bf16(v.x, v.y);
        const unsigned h1 = cvt_pk_bf16(v.z, v.w);
        const unsigned l0 = cvt_pk_bf16(v.x - ubits(h0 << 16), v.y - ubits(h0 & 0xffff0000u));
        const unsigned l1 = cvt_pk_bf16(v.z - ubits(h1 << 16), v.w - ubits(h1 & 0xffff0000u));
        *(uint2*)&xstg[xs][xb][4 * xhf]     = make_uint2(h0, h1);
        *(uint2*)&xstg[xs][xb][8 + 4 * xhf] = make_uint2(l0, l1);
    };

    // ---- init: zero h (both buffers) and xstg, stage chunk 0 ----
    for (int i = tix; i < (int)(sizeof(hh) / 4); i += NT) {
        ((unsigned*)hh)[i] = 0u;
        ((unsigned*)hl)[i] = 0u;
    }
    for (int i = tix; i < 8 * 17 * 24 / 2; i += NT) ((unsigned*)xstg)[i] = 0u;
    __syncthreads();
    float4 xbuf = {0.f, 0.f, 0.f, 0.f};
    if (stager) {
        stage(ldchunk(0));
        xbuf = ldchunk(1);
    }
    __syncthreads();

    // ---- XC[s]: x-contribution + bias for this wave's tile (32 VGPRs) ----
    f32x4 XC[8];
    #pragma unroll
    for (int s = 0; s < 8; ++s) {
        const bf16x8 Bx_ = *(const bf16x8*)&xstg[s][cc][xoff];
        XC[s] = __builtin_amdgcn_mfma_f32_16x16x32_bf16(Wx, Bx_, biasv, 0, 0, 0);
    }

    // cell ownership: unit u = 4m+q, batch cc (in-register, never exchanged)
    const int uown = 4 * m + q;
    const int piu  = (uown < 16) ? 2 * uown : 2 * (uown - 16) + 1;   // pi col
    const float TWL = 2.f * LOG2E;
    float cs = 0.f, hf = 0.f;

    for (int blk = 0; blk < NCHUNK; ++blk) {
        #pragma unroll
        for (int s = 0; s < 8; ++s) {
            const int rb = s & 1, wb = rb ^ 1;        // h ping-pong (t&1 == s&1)

            // ---- h B-frags + refill operands (all LDS reads up front) ----
            const bf16x8 Hh = *(const bf16x8*)&hh[rb][cc][8 * q];
            const bf16x8 Hl = *(const bf16x8*)&hl[rb][cc][8 * q];
            bf16x8 Bxp, Bx7;
            if (s >= 1)  Bxp = *(const bf16x8*)&xstg[s - 1][cc][xoff];
            if (s == 7)  Bx7 = *(const bf16x8*)&xstg[7][cc][xoff];

            // ---- 3 independent MFMAs (A=weights, B=h) ----
            const f32x4 z = { 0.f, 0.f, 0.f, 0.f };
            f32x4 a1 = __builtin_amdgcn_mfma_f32_16x16x32_bf16(Whi, Hh, XC[s], 0, 0, 0);
            f32x4 a2 = __builtin_amdgcn_mfma_f32_16x16x32_bf16(Whi, Hl, z, 0, 0, 0);
            f32x4 a3 = __builtin_amdgcn_mfma_f32_16x16x32_bf16(Wlo, Hh, z, 0, 0, 0);

            // ---- next-chunk XC refill (off critical path) ----
            if (s >= 1)
                XC[s - 1] = __builtin_amdgcn_mfma_f32_16x16x32_bf16(Wx, Bxp, biasv, 0, 0, 0);
            if (s == 7)
                XC[7] = __builtin_amdgcn_mfma_f32_16x16x32_bf16(Wx, Bx7, biasv, 0, 0, 0);

            // ---- stage next chunk early (s==0): consumed by refills from s==1 ----
            if (s == 0 && stager) {
                stage(xbuf);
                int nc = blk + 2;
                if (nc > NCHUNK - 1) nc = NCHUNK - 1;
                xbuf = ldchunk(nc);
            }

            // ---- per-lane cell math: C[reg] = pre-act of gate reg (i,f,g,o) ----
            const f32x4 C = (a1 + a2) + a3;
            {
                const float Ei = fexp2(C[0]);
                const float Ef = fexp2(C[1]);
                const float Eg = fexp2(C[2]);
                const float Eo = fexp2(C[3]);
                const float P  = (1.f + Eg) * (1.f + Ei);
                const float Q  = 1.f + Ef;
                const float r1 = __builtin_fmaf(Eg, -TWL, TWL);   // 2L*(1-Eg)
                const float num = __builtin_fmaf(cs, P, r1 * Q);
                const float rd  = frcp(P * Q);
                cs = num * rd;                                    // cs = 2L*c
                cs = fminf(fmaxf(cs, -CSCLAMP), CSCLAMP);
                const float W  = fexp2(cs);
                const float rh = frcp((1.f + Eo) * (W + 1.f));
                hf = (W - 1.f) * rh;                              // sigma(o)*tanh(c)
            }

            // ---- h write: cell (uown, cc) -> buf wb, hi/lo bf16 ----
            {
                const unsigned short hw16 = (unsigned short)cvt_pk_bf16(hf, hf);
                const float hlo_ = hf - ubits((unsigned)hw16 << 16);
                const unsigned short lw16 = (unsigned short)cvt_pk_bf16(hlo_, hlo_);
                hh[wb][cc][piu] = hw16;
                hl[wb][cc][piu] = lw16;
            }

            WG_BARRIER();               // the ONLY barrier per step
        }
    }

    // ---- epilogue: out[b] = sum_u h[u][b]*W_fc[u] + b_fc ----
    float part = hf * W_fc[uown];
    part += __shfl_xor(part, 16);
    part += __shfl_xor(part, 32);       // sum over this wave's 4 units
    if (lane < NBATCH) gpart[m][lane] = part;
    __syncthreads();
    if (tix < NBATCH) {
        float s = b_fc[0];
        #pragma unroll
        for (int mm = 0; mm < 8; ++mm) s += gpart[mm][tix];
        out[blockIdx.x * NBATCH + tix] = s;
    }
}

extern "C" void kernel_launch(void* const* d_in, const int* in_sizes, int n_in,
                              void* d_out, int out_size, void* d_ws, size_t ws_size,
                              hipStream_t stream) {
    const float* x    = (const float*)d_in[0];
    const float* W_ih = (const float*)d_in[1];
    const float* W_hh = (const float*)d_in[2];
    const float* b_ih = (const float*)d_in[3];
    const float* b_hh = (const float*)d_in[4];
    const float* W_fc = (const float*)d_in[5];
    const float* b_fc = (const float*)d_in[6];
    float* out = (float*)d_out;
    const int Bn = in_sizes[0] / (T_LEN * IN_D);   // 8192
    lstm_xfree<<<dim3(Bn / NBATCH), dim3(NT), 0, stream>>>(
        x, W_ih, W_hh, b_ih, b_hh, W_fc, b_fc, out);
}